// Round 1
// 849.329 us; speedup vs baseline: 1.0873x; 1.0873x over previous
//
#include <hip/hip_runtime.h>
#include <hip/hip_bf16.h>

#define NN 100000
#define INC 1024
#define HID 128
#define NE 1600000
#define NB ((NN + 255) / 256)   // 391 scan blocks

typedef float floatx4 __attribute__((ext_vector_type(4)));
typedef __bf16 bf16x8 __attribute__((ext_vector_type(8)));
typedef unsigned short ushort8v __attribute__((ext_vector_type(8)));
typedef unsigned short ushort4v __attribute__((ext_vector_type(4)));

__device__ __forceinline__ unsigned short f2bf(float f) {
    union { float f; unsigned u; } v; v.f = f;
    unsigned r = v.u + 0x7fffu + ((v.u >> 16) & 1u);   // round-to-nearest-even
    return (unsigned short)(r >> 16);
}

__device__ __forceinline__ float bf_lo(unsigned u) {
    union { unsigned u; float f; } v; v.u = u << 16; return v.f;
}
__device__ __forceinline__ float bf_hi(unsigned u) {
    union { unsigned u; float f; } v; v.u = u & 0xffff0000u; return v.f;
}

// ---- fused: zero degree histogram (blocks [0,NB)) + W transpose->bf16 (blocks [NB,NB+512)) ----
__global__ __launch_bounds__(256) void init_k(int* cnt, const float* __restrict__ W,
                                              unsigned short* __restrict__ Wt) {
    const int b = blockIdx.x;
    if (b < NB) {
        const int i = b * 256 + threadIdx.x;
        if (i < NN) cnt[i] = 0;
    } else {
        const int idx = (b - NB) * 256 + threadIdx.x;   // 131072 total
        const int n = idx >> 10, k = idx & 1023;
        Wt[idx] = f2bf(W[k * HID + n]);
    }
}

// ---- histogram destination degrees (excluding self-loop) ----
__global__ __launch_bounds__(256) void deg_edges_k(const int* __restrict__ col, int* cnt) {
    int e = blockIdx.x * 256 + threadIdx.x;
    if (e < NE) atomicAdd(&cnt[col[e]], 1);
}

// ---- exclusive scan, pass 1: per-block (256-wide); also emit dinv = rsqrt(deg+1) ----
__global__ __launch_bounds__(256) void scan1_k(const int* __restrict__ cnt,
                                               int* __restrict__ excl, int* __restrict__ bsum,
                                               float* __restrict__ dinv) {
    __shared__ int sh[256];
    const int t = threadIdx.x, b = blockIdx.x;
    const int idx = b * 256 + t;
    const int v = (idx < NN) ? cnt[idx] : 0;
    sh[t] = v;
    __syncthreads();
#pragma unroll
    for (int off = 1; off < 256; off <<= 1) {
        const int x = sh[t];
        const int y = (t >= off) ? sh[t - off] : 0;
        __syncthreads();
        sh[t] = x + y;
        __syncthreads();
    }
    if (idx < NN) {
        excl[idx] = sh[t] - v;
        dinv[idx] = rsqrtf((float)(v + 1));
    }
    if (t == 255) bsum[b] = sh[255];
}

// ---- exclusive scan, pass 2: scan the 391 block sums (single block, 512 thr) ----
__global__ __launch_bounds__(512) void scan2_k(const int* __restrict__ bsum, int* __restrict__ boff) {
    __shared__ int sh[512];
    const int t = threadIdx.x;
    const int v = (t < NB) ? bsum[t] : 0;
    sh[t] = v;
    __syncthreads();
#pragma unroll
    for (int off = 1; off < 512; off <<= 1) {
        const int x = sh[t];
        const int y = (t >= off) ? sh[t - off] : 0;
        __syncthreads();
        sh[t] = x + y;
        __syncthreads();
    }
    if (t < NB) boff[t] = sh[t] - v;
}

// ---- scan pass 3: rowptr = excl + boff; also init cursor; rowptr[NN] = NE ----
__global__ __launch_bounds__(256) void scan3_k(const int* __restrict__ excl, const int* __restrict__ boff,
                                               int* __restrict__ rowptr, int* __restrict__ cursor) {
    const int idx = blockIdx.x * 256 + threadIdx.x;
    if (idx < NN) {
        const int v = excl[idx] + boff[blockIdx.x];
        rowptr[idx] = v;
        cursor[idx] = v;
    }
    if (idx == 0) rowptr[NN] = NE;
}

// ---- bucket edges by destination: ssrc[rowptr[c] ...] = srcs of c ----
__global__ __launch_bounds__(256) void fill_k(const int* __restrict__ ei,
                                              int* cursor, int* __restrict__ ssrc) {
    const int e = blockIdx.x * 256 + threadIdx.x;
    if (e < NE) {
        const int r = ei[e];
        const int c = ei[NE + e];
        const int pos = atomicAdd(&cursor[c], 1);
        ssrc[pos] = r;
    }
}

// ---- GEMM: hp = bf16( (x @ W) * dinv[row] ), reg-prefetch double-buffered LDS ----
__global__ __launch_bounds__(256) void gemm_hp_k(
    const float* __restrict__ x, const unsigned short* __restrict__ Wt,
    const float* __restrict__ dinv, unsigned short* __restrict__ hp)
{
    __shared__ unsigned short As[2][64 * 40];
    __shared__ unsigned short Bs[2][128 * 40];
    const int tid  = threadIdx.x;
    const int lane = tid & 63;
    const int wave = tid >> 6;
    const int q    = lane >> 4;
    const int l16  = lane & 15;
    const int brow = blockIdx.x * 64;

    // staging geometry (per thread)
    const int am  = tid >> 3;          // A: 32 rows per half, 2 halves
    const int akk = (tid & 7) * 4;     // 8 threads cover 32 floats of a row
    const int bn  = tid >> 1;          // B: 128 rows, 2 threads/row
    const int bkk = (tid & 1) * 16;    // each covers 16 shorts

    floatx4 acc[8];
#pragma unroll
    for (int t = 0; t < 8; ++t) acc[t] = (floatx4){0.f, 0.f, 0.f, 0.f};

    float4   va[2];
    ushort8v vb[2];

    // prologue: stage k0 = 0 into registers
    {
#pragma unroll
        for (int h = 0; h < 2; ++h) {
            const int g = brow + am + h * 32;
            float4 v = make_float4(0.f, 0.f, 0.f, 0.f);
            if (g < NN) v = *(const float4*)&x[(size_t)g * INC + akk];
            va[h] = v;
        }
        vb[0] = *(const ushort8v*)&Wt[(size_t)bn * INC + bkk];
        vb[1] = *(const ushort8v*)&Wt[(size_t)bn * INC + bkk + 8];
    }

    int buf = 0;
    for (int k0 = 0; k0 < INC; k0 += 32) {
        // regs -> LDS[buf]
        {
#pragma unroll
            for (int h = 0; h < 2; ++h) {
                ushort4v w;
                w.x = f2bf(va[h].x); w.y = f2bf(va[h].y);
                w.z = f2bf(va[h].z); w.w = f2bf(va[h].w);
                *(ushort4v*)&As[buf][(am + h * 32) * 40 + akk] = w;
            }
            *(ushort8v*)&Bs[buf][bn * 40 + bkk]     = vb[0];
            *(ushort8v*)&Bs[buf][bn * 40 + bkk + 8] = vb[1];
        }
        __syncthreads();

        // issue next tile's global loads (overlap with MFMA below)
        const int kn = k0 + 32;
        if (kn < INC) {
#pragma unroll
            for (int h = 0; h < 2; ++h) {
                const int g = brow + am + h * 32;
                float4 v = make_float4(0.f, 0.f, 0.f, 0.f);
                if (g < NN) v = *(const float4*)&x[(size_t)g * INC + kn + akk];
                va[h] = v;
            }
            vb[0] = *(const ushort8v*)&Wt[(size_t)bn * INC + kn + bkk];
            vb[1] = *(const ushort8v*)&Wt[(size_t)bn * INC + kn + bkk + 8];
        }

        const bf16x8 af = *(const bf16x8*)&As[buf][(wave * 16 + l16) * 40 + q * 8];
#pragma unroll
        for (int t = 0; t < 8; ++t) {
            const bf16x8 bfv = *(const bf16x8*)&Bs[buf][(t * 16 + l16) * 40 + q * 8];
            acc[t] = __builtin_amdgcn_mfma_f32_16x16x32_bf16(af, bfv, acc[t], 0, 0, 0);
        }
        buf ^= 1;
        // single barrier per K-step: a wave only reaches the NEXT store into this
        // buffer after passing the next iteration's barrier, by which time all
        // waves' ds_reads of it have drained (lgkmcnt(0) precedes s_barrier).
    }

#pragma unroll
    for (int r = 0; r < 4; ++r) {
        const int row = brow + wave * 16 + q * 4 + r;
        if (row < NN) {
            const float d = dinv[row];
#pragma unroll
            for (int t = 0; t < 8; ++t) {
                const int col = t * 16 + l16;
                hp[(size_t)row * HID + col] = f2bf(acc[t][r] * d);
            }
        }
    }
}

// ---- aggregation: one wave per dst; out[d] = dinv[d] * (hp[d] + sum hp[src]) ----
// hp is bf16: each lane owns 2 columns packed in one dword (256 B/row, coalesced).
__global__ __launch_bounds__(256) void agg_k(const int* __restrict__ rowptr,
                                             const int* __restrict__ ssrc,
                                             const unsigned short* __restrict__ hp,
                                             const float* __restrict__ dinv,
                                             float* __restrict__ out)
{
    const int w = (blockIdx.x * 256 + threadIdx.x) >> 6;   // dst node
    const int lane = threadIdx.x & 63;
    if (w >= NN) return;
    const int s = rowptr[w];
    const int e = rowptr[w + 1];
    const unsigned* hp32 = (const unsigned*)hp;            // row stride = 64 dwords

    const unsigned uself = hp32[(size_t)w * 64 + lane];
    float ax = bf_lo(uself), ay = bf_hi(uself);

    for (int i = s; i < e; i += 64) {
        const int rem = e - i;
        const int cnt = rem < 64 ? rem : 64;
        int srcv = 0;
        if (lane < rem) srcv = ssrc[i + lane];
        int j = 0;
        for (; j + 4 <= cnt; j += 4) {
            const int s0 = __shfl(srcv, j + 0);
            const int s1 = __shfl(srcv, j + 1);
            const int s2 = __shfl(srcv, j + 2);
            const int s3 = __shfl(srcv, j + 3);
            const unsigned v0 = hp32[(size_t)s0 * 64 + lane];
            const unsigned v1 = hp32[(size_t)s1 * 64 + lane];
            const unsigned v2 = hp32[(size_t)s2 * 64 + lane];
            const unsigned v3 = hp32[(size_t)s3 * 64 + lane];
            ax += bf_lo(v0) + bf_lo(v1) + bf_lo(v2) + bf_lo(v3);
            ay += bf_hi(v0) + bf_hi(v1) + bf_hi(v2) + bf_hi(v3);
        }
        for (; j < cnt; ++j) {
            const int sj = __shfl(srcv, j);
            const unsigned v = hp32[(size_t)sj * 64 + lane];
            ax += bf_lo(v);
            ay += bf_hi(v);
        }
    }

    const float d = dinv[w];
    float2 r;
    r.x = ax * d;
    r.y = ay * d;
    *(float2*)&out[(size_t)w * HID + (size_t)lane * 2] = r;
}

extern "C" void kernel_launch(void* const* d_in, const int* in_sizes, int n_in,
                              void* d_out, int out_size, void* d_ws, size_t ws_size,
                              hipStream_t stream) {
    const float* x  = (const float*)d_in[0];
    const float* W  = (const float*)d_in[1];
    const int*   ei = (const int*)d_in[2];
    float* out = (float*)d_out;

    // workspace layout (bytes)
    char* p = (char*)d_ws;
    unsigned short* hp = (unsigned short*)p; p += (size_t)NN * HID * 2;  // 25.6 MB
    int*   cnt     = (int*)p;              p += (size_t)NN * 4;
    int*   rowptr  = (int*)p;              p += (size_t)(NN + 4) * 4;
    int*   cursor  = (int*)p;              p += (size_t)NN * 4;
    int*   excl    = (int*)p;              p += (size_t)NN * 4;
    float* dinv    = (float*)p;            p += (size_t)NN * 4;
    unsigned short* Wt = (unsigned short*)p; p += (size_t)INC * HID * 2;
    int*   bsum    = (int*)p;              p += 512 * 4;
    int*   boff    = (int*)p;              p += 512 * 4;
    int*   ssrc    = (int*)p;              p += (size_t)NE * 4;          // 6.4 MB

    init_k     <<<NB + (INC * HID) / 256, 256, 0, stream>>>(cnt, W, Wt);
    deg_edges_k<<<(NE + 255) / 256, 256, 0, stream>>>(ei + NE, cnt);
    scan1_k    <<<NB, 256, 0, stream>>>(cnt, excl, bsum, dinv);
    scan2_k    <<<1, 512, 0, stream>>>(bsum, boff);
    scan3_k    <<<NB, 256, 0, stream>>>(excl, boff, rowptr, cursor);
    fill_k     <<<(NE + 255) / 256, 256, 0, stream>>>(ei, cursor, ssrc);
    gemm_hp_k  <<<(NN + 63) / 64, 256, 0, stream>>>(x, Wt, dinv, hp);
    agg_k      <<<(NN * 64 + 255) / 256, 256, 0, stream>>>(rowptr, ssrc, hp, dinv, out);
}